// Round 3
// baseline (403.391 us; speedup 1.0000x reference)
//
#include <hip/hip_runtime.h>
#include <cstdint>
#include <cstddef>

#define EPS 1e-6f

typedef short bf16x8 __attribute__((ext_vector_type(8)));
typedef float f32x4  __attribute__((ext_vector_type(4)));

__device__ __forceinline__ short f2bf(float x) {
    uint32_t u = __builtin_bit_cast(uint32_t, x);
    return (short)((u + 0x7FFFu + ((u >> 16) & 1u)) >> 16);
}
__device__ __forceinline__ float bf2f(short s) {
    uint32_t u = ((uint32_t)(uint16_t)s) << 16;
    return __builtin_bit_cast(float, u);
}

// ---------------------------------------------------------------------------
// Kernel S: per-batch mask scan -> compacted valid list + counts.
// 16 elems/thread local prefix + one 256-wide block scan.
// ---------------------------------------------------------------------------
__global__ __launch_bounds__(256) void k_scan(const void* __restrict__ maskp,
                                              int* __restrict__ v_list,
                                              int* __restrict__ counts) {
    __shared__ int sc[256];
    __shared__ int mode_s;
    const int tid = threadIdx.x;
    const int b = blockIdx.x;
    const uint32_t* mi = (const uint32_t*)maskp;

    if (tid == 0) mode_s = 0;
    __syncthreads();
    int bad = 0;
    for (int k = tid; k < 1024; k += 256) bad |= (mi[k] > 1u) ? 1 : 0;
    if (bad) mode_s = 1;  // racy same-value write is fine
    __syncthreads();

    int m[16];
    if (mode_s) {
        const uint4 v = *(const uint4*)((const uint8_t*)maskp + (b << 12) + tid * 16);
        const uint32_t ws[4] = {v.x, v.y, v.z, v.w};
#pragma unroll
        for (int w4 = 0; w4 < 4; ++w4)
#pragma unroll
            for (int e = 0; e < 4; ++e)
                m[w4 * 4 + e] = ((ws[w4] >> (8 * e)) & 0xffu) ? 1 : 0;
    } else {
        const uint32_t* p = mi + (b << 12) + tid * 16;
#pragma unroll
        for (int q = 0; q < 16; ++q) m[q] = p[q] ? 1 : 0;
    }
    int cl = 0;
#pragma unroll
    for (int q = 0; q < 16; ++q) cl += m[q];
    sc[tid] = cl;
    __syncthreads();
    for (int off = 1; off < 256; off <<= 1) {
        int v = sc[tid];
        int a = (tid >= off) ? sc[tid - off] : 0;
        __syncthreads();
        sc[tid] = v + a;
        __syncthreads();
    }
    int pos = sc[tid] - cl;
#pragma unroll
    for (int q = 0; q < 16; ++q) {
        if (m[q]) v_list[(b << 12) + pos++] = tid * 16 + q;
    }
    if (tid == 255) counts[b] = sc[255];
}

// ---------------------------------------------------------------------------
// Kernel conv2: fp32 -> bf16 (RNE) for two arrays in one launch.
// ---------------------------------------------------------------------------
__global__ __launch_bounds__(256) void k_conv2(
    const float* __restrict__ s1, short* __restrict__ d1, int n1,
    const float* __restrict__ s2, short* __restrict__ d2, int n2) {
    const int gid = blockIdx.x * 256 + threadIdx.x;
    const float* src; short* dst; int idx;
    if (gid < n1) { src = s1; dst = d1; idx = gid; }
    else if (gid < n1 + n2) { src = s2; dst = d2; idx = gid - n1; }
    else return;
    const float4 v = ((const float4*)src)[idx];
    short4 o;
    o.x = f2bf(v.x); o.y = f2bf(v.y); o.z = f2bf(v.z); o.w = f2bf(v.w);
    ((short4*)dst)[idx] = o;
}

// ---------------------------------------------------------------------------
// Kernel TP: token rmsnorm -> bf16 rows. One wave per row (1024 elems).
// ---------------------------------------------------------------------------
__global__ __launch_bounds__(256) void k_tokprep(const float* __restrict__ tokens,
                                                 const float* __restrict__ w_pre,
                                                 short* __restrict__ tokbf) {
    const int tid = threadIdx.x, lane = tid & 63, wave = tid >> 6;
    const int row = blockIdx.x * 4 + wave;
    const float* xp = tokens + (size_t)row * 1024 + lane * 16;
    float4 x[4];
#pragma unroll
    for (int q = 0; q < 4; ++q) x[q] = *(const float4*)&xp[q * 4];
    float ss = 0.f;
#pragma unroll
    for (int q = 0; q < 4; ++q)
        ss += x[q].x * x[q].x + x[q].y * x[q].y + x[q].z * x[q].z + x[q].w * x[q].w;
#pragma unroll
    for (int off = 32; off > 0; off >>= 1) ss += __shfl_down(ss, off);
    ss = __shfl(ss, 0);
    const float r = rsqrtf(ss * (1.0f / 1024.0f) + EPS);
    const float* wp = w_pre + lane * 16;
    short* op = tokbf + (size_t)row * 1024 + lane * 16;
#pragma unroll
    for (int h = 0; h < 2; ++h) {
        bf16x8 o;
#pragma unroll
        for (int q = 0; q < 2; ++q) {
            const float4 wv = *(const float4*)&wp[h * 8 + q * 4];
            const float4 xv = x[h * 2 + q];
            o[q * 4 + 0] = f2bf(xv.x * wv.x * r);
            o[q * 4 + 1] = f2bf(xv.y * wv.y * r);
            o[q * 4 + 2] = f2bf(xv.z * wv.z * r);
            o[q * 4 + 3] = f2bf(xv.w * wv.w * r);
        }
        *(bf16x8*)&op[h * 8] = o;
    }
}

// ---------------------------------------------------------------------------
// Kernel GT: token GEMM feats_pre = tokn @ W_down^T, bf16 MFMA 128x64 tiles
// (256 blocks -> full chip).
// ---------------------------------------------------------------------------
__global__ __launch_bounds__(256) void k_gemm_tok(const short* __restrict__ tokbf,
                                                  const short* __restrict__ Wdbf,
                                                  float* __restrict__ feats) {
    __shared__ short As[128 * 32];
    __shared__ short Bs[64 * 32];
    const int tid = threadIdx.x, lane = tid & 63, w = tid >> 6;
    const int mt = blockIdx.x >> 3, nt = blockIdx.x & 7;
    const int wm = w >> 1, wn = w & 1;
    const short* hA = tokbf + (size_t)mt * 128 * 1024;
    const short* wB = Wdbf + (size_t)nt * 64 * 1024;

    f32x4 acc[4][2];
#pragma unroll
    for (int mi = 0; mi < 4; ++mi)
#pragma unroll
        for (int ni = 0; ni < 2; ++ni) acc[mi][ni] = (f32x4)0.f;

    const int rA = lane & 15, q8 = (lane >> 4) * 8;
    for (int kk = 0; kk < 1024; kk += 32) {
#pragma unroll
        for (int q = 0; q < 2; ++q) {
            const int cid = (w * 2 + q) * 64 + lane;
            const int r = cid >> 2, kc = cid & 3;
            __builtin_amdgcn_global_load_lds(
                (const __attribute__((address_space(1))) uint32_t*)(hA + (size_t)r * 1024 + kk + kc * 8),
                (__attribute__((address_space(3))) uint32_t*)&As[(w * 2 + q) * 512], 16, 0, 0);
        }
        {
            const int cid = tid;
            const int r = cid >> 2, kc = cid & 3;
            __builtin_amdgcn_global_load_lds(
                (const __attribute__((address_space(1))) uint32_t*)(wB + (size_t)r * 1024 + kk + kc * 8),
                (__attribute__((address_space(3))) uint32_t*)&Bs[w * 512], 16, 0, 0);
        }
        __syncthreads();
        bf16x8 af[4], bfr[2];
#pragma unroll
        for (int mi = 0; mi < 4; ++mi)
            af[mi] = *(const bf16x8*)&As[(wm * 64 + mi * 16 + rA) * 32 + q8];
#pragma unroll
        for (int ni = 0; ni < 2; ++ni)
            bfr[ni] = *(const bf16x8*)&Bs[(wn * 32 + ni * 16 + rA) * 32 + q8];
#pragma unroll
        for (int mi = 0; mi < 4; ++mi)
#pragma unroll
            for (int ni = 0; ni < 2; ++ni)
                acc[mi][ni] = __builtin_amdgcn_mfma_f32_16x16x32_bf16(af[mi], bfr[ni], acc[mi][ni], 0, 0, 0);
        __syncthreads();
    }
    const int rowb = mt * 128 + wm * 64 + (lane >> 4) * 4;
    const int colb = nt * 64 + wn * 32 + (lane & 15);
#pragma unroll
    for (int mi = 0; mi < 4; ++mi)
#pragma unroll
        for (int ni = 0; ni < 2; ++ni)
#pragma unroll
            for (int rg = 0; rg < 4; ++rg)
                feats[(size_t)(rowb + mi * 16 + rg) * 512 + colb + ni * 16] = acc[mi][ni][rg];
}

// ---------------------------------------------------------------------------
// Kernel A3: one wave per token: rmsnorm(feats_pre, w_tok) -> silu -> W_proj.
// ---------------------------------------------------------------------------
__global__ __launch_bounds__(64) void k_params(
    const float* __restrict__ feats_pre, const float* __restrict__ w_tok,
    const float* __restrict__ W_proj, float* __restrict__ params) {
    const int tk = blockIdx.x;
    const int lane = threadIdx.x;
    const int d0 = lane * 8;
    const float* fp = feats_pre + (size_t)tk * 512 + d0;
    const float4 f0 = *(const float4*)&fp[0];
    const float4 f1 = *(const float4*)&fp[4];
    float ss = f0.x * f0.x + f0.y * f0.y + f0.z * f0.z + f0.w * f0.w
             + f1.x * f1.x + f1.y * f1.y + f1.z * f1.z + f1.w * f1.w;
#pragma unroll
    for (int off = 32; off > 0; off >>= 1) ss += __shfl_down(ss, off);
    ss = __shfl(ss, 0);
    const float rms = rsqrtf(ss * (1.0f / 512.0f) + EPS);

    const float4 wt0 = *(const float4*)&w_tok[d0];
    const float4 wt1 = *(const float4*)&w_tok[d0 + 4];
    float fv[8] = {f0.x, f0.y, f0.z, f0.w, f1.x, f1.y, f1.z, f1.w};
    float wv[8] = {wt0.x, wt0.y, wt0.z, wt0.w, wt1.x, wt1.y, wt1.z, wt1.w};
    float s[8];
#pragma unroll
    for (int j = 0; j < 8; ++j) {
        const float v = fv[j] * wv[j] * rms;
        s[j] = v / (1.0f + expf(-v));
    }
    float p[3];
#pragma unroll
    for (int q = 0; q < 3; ++q) {
        const float* Wp = W_proj + (size_t)q * 512 + d0;
        const float4 a = *(const float4*)&Wp[0];
        const float4 c = *(const float4*)&Wp[4];
        p[q] = s[0] * a.x + s[1] * a.y + s[2] * a.z + s[3] * a.w
             + s[4] * c.x + s[5] * c.y + s[6] * c.z + s[7] * c.w;
#pragma unroll
        for (int off = 32; off > 0; off >>= 1) p[q] += __shfl_down(p[q], off);
    }
    if (lane == 0) {
        float* po = params + (size_t)tk * 4;
        po[0] = 1.0f + p[0];
        po[1] = p[1];
        po[2] = 1.0f / (1.0f + expf(-p[2]));
    }
}

// ---------------------------------------------------------------------------
// Kernel CP: char prep. One wave per compact slot j: rmsnorm -> modulated silu
// -> bf16 h row; also stores cnp = (1-g)*cn as bf16 and g per slot.
// Zeroes h pad rows up to cnt rounded to 128.
// ---------------------------------------------------------------------------
__global__ __launch_bounds__(256) void k_prep(
    const float* __restrict__ chars, const float* __restrict__ w_char,
    const float* __restrict__ params, const int* __restrict__ v_list,
    const int* __restrict__ counts, short* __restrict__ hb,
    short* __restrict__ cnp, float* __restrict__ g_l) {
    const int tid = threadIdx.x, lane = tid & 63, wave = tid >> 6;
    const int b = blockIdx.x >> 10;
    const int j = (blockIdx.x & 1023) * 4 + wave;
    const int cnt = counts[b];
    const int cpad = (cnt + 127) & ~127;
    if (j >= cpad) return;
    short* hrow = hb + ((size_t)(b << 12) + j) * 512 + lane * 8;
    if (j >= cnt) {
        *(bf16x8*)hrow = (bf16x8)0;
        return;
    }
    const int i = v_list[(b << 12) + j];
    const float* xp = chars + ((size_t)(b << 12) + i) * 512 + lane * 8;
    const float4 x0 = *(const float4*)&xp[0];
    const float4 x1 = *(const float4*)&xp[4];
    float ss = x0.x * x0.x + x0.y * x0.y + x0.z * x0.z + x0.w * x0.w
             + x1.x * x1.x + x1.y * x1.y + x1.z * x1.z + x1.w * x1.w;
#pragma unroll
    for (int off = 32; off > 0; off >>= 1) ss += __shfl_down(ss, off);
    ss = __shfl(ss, 0);
    const float rms = rsqrtf(ss * (1.0f / 512.0f) + EPS);
    const float* pp = params + (size_t)((b << 8) + (i >> 4)) * 4;
    const float s1 = pp[0], sh = pp[1], g = pp[2];
    const float4 w0 = *(const float4*)&w_char[lane * 8];
    const float4 w1 = *(const float4*)&w_char[lane * 8 + 4];
    float xv[8] = {x0.x, x0.y, x0.z, x0.w, x1.x, x1.y, x1.z, x1.w};
    float wv[8] = {w0.x, w0.y, w0.z, w0.w, w1.x, w1.y, w1.z, w1.w};
    bf16x8 oh, oc;
    const float gm1 = 1.0f - g;
#pragma unroll
    for (int q = 0; q < 8; ++q) {
        const float cn = wv[q] * xv[q] * rms;
        const float a = cn * s1 + sh;
        oh[q] = f2bf(a / (1.0f + expf(-a)));
        oc[q] = f2bf(gm1 * cn);
    }
    *(bf16x8*)hrow = oh;
    *(bf16x8*)(cnp + ((size_t)(b << 12) + j) * 512 + lane * 8) = oc;
    if (lane == 0) g_l[(b << 12) + j] = g;
}

// ---------------------------------------------------------------------------
// Kernel F: fill output rows j >= counts[b] with filler_embed.
// ---------------------------------------------------------------------------
__global__ __launch_bounds__(256) void k_fill(
    const float* __restrict__ filler, const int* __restrict__ counts,
    float* __restrict__ out) {
    const int gid = blockIdx.x * 256 + threadIdx.x;
    const size_t e4 = (size_t)gid * 4;
    const int slot = gid >> 7;
    const int b = slot >> 12;
    const int j = slot & 4095;
    if (j >= counts[b]) {
        const int e0 = (int)(e4 & 511);
        *(float4*)&out[e4] = *(const float4*)&filler[e0];
    }
}

// ---------------------------------------------------------------------------
// Kernel GF: fusion GEMM out[j<cnt] = g*(h @ Wfus^T) + cnp, bf16 MFMA 128x128
// tiles over compacted rows. Epilogue transposes acc through LDS (aliased over
// the A/B staging buffers) for coalesced float4 stores + sequential cnp reads.
// ---------------------------------------------------------------------------
__global__ __launch_bounds__(256) void k_gemm_fus(
    const short* __restrict__ hb, const short* __restrict__ Wbf,
    const short* __restrict__ cnp, const float* __restrict__ g_l,
    const int* __restrict__ counts, float* __restrict__ out) {
    __shared__ union SM {
        struct { short A[128 * 32]; short B[128 * 32]; } ab;
        float ep[32][132];
    } sm;
    __shared__ float g_s[128];
    const int tid = threadIdx.x, lane = tid & 63, w = tid >> 6;
    const int b = blockIdx.x >> 7;
    const int mt = (blockIdx.x >> 2) & 31;
    const int nt = blockIdx.x & 3;
    const int cnt = counts[b];
    const int row0 = mt * 128;
    if (row0 >= cnt) return;
    const int wm = w >> 1, wn = w & 1;

    if (tid < 128) {
        const int j = row0 + tid;
        g_s[tid] = (j < cnt) ? g_l[(b << 12) + j] : 0.f;
    }

    const short* hA = hb + ((size_t)(b << 12) + row0) * 512;
    const short* wB = Wbf + (size_t)nt * 128 * 512;

    f32x4 acc[4][4];
#pragma unroll
    for (int mi = 0; mi < 4; ++mi)
#pragma unroll
        for (int ni = 0; ni < 4; ++ni) acc[mi][ni] = (f32x4)0.f;

    const int rA = lane & 15, q8 = (lane >> 4) * 8;
    for (int kk = 0; kk < 512; kk += 32) {
#pragma unroll
        for (int q = 0; q < 2; ++q) {
            const int cid = (w * 2 + q) * 64 + lane;
            const int r = cid >> 2, kc = cid & 3;
            const size_t go = (size_t)r * 512 + kk + kc * 8;
            __builtin_amdgcn_global_load_lds(
                (const __attribute__((address_space(1))) uint32_t*)(hA + go),
                (__attribute__((address_space(3))) uint32_t*)&sm.ab.A[(w * 2 + q) * 512], 16, 0, 0);
            __builtin_amdgcn_global_load_lds(
                (const __attribute__((address_space(1))) uint32_t*)(wB + go),
                (__attribute__((address_space(3))) uint32_t*)&sm.ab.B[(w * 2 + q) * 512], 16, 0, 0);
        }
        __syncthreads();
        bf16x8 af[4], bfr[4];
#pragma unroll
        for (int mi = 0; mi < 4; ++mi)
            af[mi] = *(const bf16x8*)&sm.ab.A[(wm * 64 + mi * 16 + rA) * 32 + q8];
#pragma unroll
        for (int ni = 0; ni < 4; ++ni)
            bfr[ni] = *(const bf16x8*)&sm.ab.B[(wn * 64 + ni * 16 + rA) * 32 + q8];
#pragma unroll
        for (int mi = 0; mi < 4; ++mi)
#pragma unroll
            for (int ni = 0; ni < 4; ++ni)
                acc[mi][ni] = __builtin_amdgcn_mfma_f32_16x16x32_bf16(af[mi], bfr[ni], acc[mi][ni], 0, 0, 0);
        __syncthreads();
    }

    // Epilogue: 4 passes; each stages 32 rows x 128 cols f32 in LDS, then
    // 8 threads/row emit 4 coalesced float4 stores each.
    const int r5 = tid >> 3;            // 0..31: row within the ep stage
    const int c0 = (tid & 7) * 16;      // tile-local col group
    const int cg = nt * 128 + c0;       // global col
#pragma unroll
    for (int mi = 0; mi < 4; ++mi) {
#pragma unroll
        for (int ni = 0; ni < 4; ++ni)
#pragma unroll
            for (int rg = 0; rg < 4; ++rg)
                sm.ep[wm * 16 + (lane >> 4) * 4 + rg][wn * 64 + ni * 16 + (lane & 15)] = acc[mi][ni][rg];
        __syncthreads();
        const int jl = (r5 < 16) ? (mi * 16 + r5) : (64 + mi * 16 + (r5 - 16));
        const int j = row0 + jl;
        if (j < cnt) {
            const float g = g_s[jl];
            const short* cp = cnp + ((size_t)(b << 12) + j) * 512 + cg;
            const bf16x8 cv0 = *(const bf16x8*)cp;
            const bf16x8 cv1 = *(const bf16x8*)(cp + 8);
            float cn16[16];
#pragma unroll
            for (int e = 0; e < 8; ++e) { cn16[e] = bf2f(cv0[e]); cn16[8 + e] = bf2f(cv1[e]); }
            float* op = out + ((size_t)(b << 12) + j) * 512 + cg;
#pragma unroll
            for (int q = 0; q < 4; ++q) {
                float4 o;
                o.x = g * sm.ep[r5][c0 + q * 4 + 0] + cn16[q * 4 + 0];
                o.y = g * sm.ep[r5][c0 + q * 4 + 1] + cn16[q * 4 + 1];
                o.z = g * sm.ep[r5][c0 + q * 4 + 2] + cn16[q * 4 + 2];
                o.w = g * sm.ep[r5][c0 + q * 4 + 3] + cn16[q * 4 + 3];
                *(float4*)&op[q * 4] = o;
            }
        }
        __syncthreads();
    }
}

// ---------------------------------------------------------------------------
extern "C" void kernel_launch(void* const* d_in, const int* in_sizes, int n_in,
                              void* d_out, int out_size, void* d_ws, size_t ws_size,
                              hipStream_t stream) {
    const float* tokens = (const float*)d_in[0];
    const float* chars  = (const float*)d_in[2];
    const void*  cmask  = d_in[3];
    const float* filler = (const float*)d_in[4];
    const float* w_pre  = (const float*)d_in[5];
    const float* w_tok  = (const float*)d_in[6];
    const float* w_char = (const float*)d_in[7];
    const float* W_down = (const float*)d_in[8];
    const float* W_proj = (const float*)d_in[9];
    const float* W_fus  = (const float*)d_in[10];
    float* out = (float*)d_out;

    // workspace layout (~146 MB)
    float* feats_pre = (float*)d_ws;                          // 4096*512 f32
    float* params    = feats_pre + (size_t)4096 * 512;        // 4096*4 f32
    int*   counts    = (int*)(params + (size_t)4096 * 4);     // 16
    int*   v_list    = counts + 16;                           // 65536
    float* g_l       = (float*)(v_list + 65536);              // 65536
    short* Wbf       = (short*)(g_l + 65536);                 // 512*512 bf16
    short* Wdbf      = Wbf + (size_t)512 * 512;               // 512*1024 bf16
    short* tokbf     = Wdbf + (size_t)512 * 1024;             // 4096*1024 bf16
    short* hb        = tokbf + (size_t)4096 * 1024;           // 16*4096*512 bf16
    short* cnp       = hb + (size_t)16 * 4096 * 512;          // 16*4096*512 bf16

    k_scan<<<16, 256, 0, stream>>>(cmask, v_list, counts);
    k_conv2<<<768, 256, 0, stream>>>(W_fus, Wbf, 65536, W_down, Wdbf, 131072);
    k_tokprep<<<1024, 256, 0, stream>>>(tokens, w_pre, tokbf);
    k_gemm_tok<<<256, 256, 0, stream>>>(tokbf, Wdbf, feats_pre);
    k_params<<<4096, 64, 0, stream>>>(feats_pre, w_tok, W_proj, params);
    k_prep<<<16384, 256, 0, stream>>>(chars, w_char, params, v_list, counts, hb, cnp, g_l);
    k_fill<<<32768, 256, 0, stream>>>(filler, counts, out);
    k_gemm_fus<<<2048, 256, 0, stream>>>(hb, Wbf, cnp, g_l, counts, out);
}

// Round 4
// 387.176 us; speedup vs baseline: 1.0419x; 1.0419x over previous
//
#include <hip/hip_runtime.h>
#include <cstdint>
#include <cstddef>

#define EPS 1e-6f

typedef short bf16x8 __attribute__((ext_vector_type(8)));
typedef float f32x4  __attribute__((ext_vector_type(4)));

__device__ __forceinline__ short f2bf(float x) {
    uint32_t u = __builtin_bit_cast(uint32_t, x);
    return (short)((u + 0x7FFFu + ((u >> 16) & 1u)) >> 16);
}
__device__ __forceinline__ float bf2f(short s) {
    uint32_t u = ((uint32_t)(uint16_t)s) << 16;
    return __builtin_bit_cast(float, u);
}

// ---------------------------------------------------------------------------
// Kernel S+C: blocks 0..15 = per-batch mask scan -> compacted list + counts.
// blocks 16..783 = fp32->bf16 conversion of W_fus and W_down.
// ---------------------------------------------------------------------------
__global__ __launch_bounds__(256) void k_scan_conv(
    const void* __restrict__ maskp, int* __restrict__ v_list,
    int* __restrict__ counts,
    const float* __restrict__ s1, short* __restrict__ d1, int n1,
    const float* __restrict__ s2, short* __restrict__ d2, int n2) {
    const int tid = threadIdx.x;
    if (blockIdx.x >= 16) {
        const int gid = (blockIdx.x - 16) * 256 + tid;
        const float* src; short* dst; int idx;
        if (gid < n1) { src = s1; dst = d1; idx = gid; }
        else if (gid < n1 + n2) { src = s2; dst = d2; idx = gid - n1; }
        else return;
        const float4 v = ((const float4*)src)[idx];
        short4 o;
        o.x = f2bf(v.x); o.y = f2bf(v.y); o.z = f2bf(v.z); o.w = f2bf(v.w);
        ((short4*)dst)[idx] = o;
        return;
    }
    __shared__ int sc[256];
    __shared__ int mode_s;
    const int b = blockIdx.x;
    const uint32_t* mi = (const uint32_t*)maskp;

    if (tid == 0) mode_s = 0;
    __syncthreads();
    int bad = 0;
    for (int k = tid; k < 1024; k += 256) bad |= (mi[k] > 1u) ? 1 : 0;
    if (bad) mode_s = 1;  // racy same-value write is fine
    __syncthreads();

    int m[16];
    if (mode_s) {
        const uint4 v = *(const uint4*)((const uint8_t*)maskp + (b << 12) + tid * 16);
        const uint32_t ws[4] = {v.x, v.y, v.z, v.w};
#pragma unroll
        for (int w4 = 0; w4 < 4; ++w4)
#pragma unroll
            for (int e = 0; e < 4; ++e)
                m[w4 * 4 + e] = ((ws[w4] >> (8 * e)) & 0xffu) ? 1 : 0;
    } else {
        const uint32_t* p = mi + (b << 12) + tid * 16;
#pragma unroll
        for (int q = 0; q < 16; ++q) m[q] = p[q] ? 1 : 0;
    }
    int cl = 0;
#pragma unroll
    for (int q = 0; q < 16; ++q) cl += m[q];
    sc[tid] = cl;
    __syncthreads();
    for (int off = 1; off < 256; off <<= 1) {
        int v = sc[tid];
        int a = (tid >= off) ? sc[tid - off] : 0;
        __syncthreads();
        sc[tid] = v + a;
        __syncthreads();
    }
    int pos = sc[tid] - cl;
#pragma unroll
    for (int q = 0; q < 16; ++q) {
        if (m[q]) v_list[(b << 12) + pos++] = tid * 16 + q;
    }
    if (tid == 255) counts[b] = sc[255];
}

// ---------------------------------------------------------------------------
// Kernel TP: token rmsnorm -> bf16 rows. One wave per row (1024 elems).
// ---------------------------------------------------------------------------
__global__ __launch_bounds__(256) void k_tokprep(const float* __restrict__ tokens,
                                                 const float* __restrict__ w_pre,
                                                 short* __restrict__ tokbf) {
    const int tid = threadIdx.x, lane = tid & 63, wave = tid >> 6;
    const int row = blockIdx.x * 4 + wave;
    const float* xp = tokens + (size_t)row * 1024 + lane * 16;
    float4 x[4];
#pragma unroll
    for (int q = 0; q < 4; ++q) x[q] = *(const float4*)&xp[q * 4];
    float ss = 0.f;
#pragma unroll
    for (int q = 0; q < 4; ++q)
        ss += x[q].x * x[q].x + x[q].y * x[q].y + x[q].z * x[q].z + x[q].w * x[q].w;
#pragma unroll
    for (int off = 32; off > 0; off >>= 1) ss += __shfl_down(ss, off);
    ss = __shfl(ss, 0);
    const float r = rsqrtf(ss * (1.0f / 1024.0f) + EPS);
    const float* wp = w_pre + lane * 16;
    short* op = tokbf + (size_t)row * 1024 + lane * 16;
#pragma unroll
    for (int h = 0; h < 2; ++h) {
        bf16x8 o;
#pragma unroll
        for (int q = 0; q < 2; ++q) {
            const float4 wv = *(const float4*)&wp[h * 8 + q * 4];
            const float4 xv = x[h * 2 + q];
            o[q * 4 + 0] = f2bf(xv.x * wv.x * r);
            o[q * 4 + 1] = f2bf(xv.y * wv.y * r);
            o[q * 4 + 2] = f2bf(xv.z * wv.z * r);
            o[q * 4 + 3] = f2bf(xv.w * wv.w * r);
        }
        *(bf16x8*)&op[h * 8] = o;
    }
}

// ---------------------------------------------------------------------------
// Kernel GT: token GEMM feats_pre = tokn @ W_down^T, bf16 MFMA 128x64 tiles.
// ---------------------------------------------------------------------------
__global__ __launch_bounds__(256) void k_gemm_tok(const short* __restrict__ tokbf,
                                                  const short* __restrict__ Wdbf,
                                                  float* __restrict__ feats) {
    __shared__ short As[128 * 32];
    __shared__ short Bs[64 * 32];
    const int tid = threadIdx.x, lane = tid & 63, w = tid >> 6;
    const int mt = blockIdx.x >> 3, nt = blockIdx.x & 7;
    const int wm = w >> 1, wn = w & 1;
    const short* hA = tokbf + (size_t)mt * 128 * 1024;
    const short* wB = Wdbf + (size_t)nt * 64 * 1024;

    f32x4 acc[4][2];
#pragma unroll
    for (int mi = 0; mi < 4; ++mi)
#pragma unroll
        for (int ni = 0; ni < 2; ++ni) acc[mi][ni] = (f32x4)0.f;

    const int rA = lane & 15, q8 = (lane >> 4) * 8;
    for (int kk = 0; kk < 1024; kk += 32) {
#pragma unroll
        for (int q = 0; q < 2; ++q) {
            const int cid = (w * 2 + q) * 64 + lane;
            const int r = cid >> 2, kc = cid & 3;
            __builtin_amdgcn_global_load_lds(
                (const __attribute__((address_space(1))) uint32_t*)(hA + (size_t)r * 1024 + kk + kc * 8),
                (__attribute__((address_space(3))) uint32_t*)&As[(w * 2 + q) * 512], 16, 0, 0);
        }
        {
            const int r = tid >> 2, kc = tid & 3;
            __builtin_amdgcn_global_load_lds(
                (const __attribute__((address_space(1))) uint32_t*)(wB + (size_t)r * 1024 + kk + kc * 8),
                (__attribute__((address_space(3))) uint32_t*)&Bs[w * 512], 16, 0, 0);
        }
        __syncthreads();
        bf16x8 af[4], bfr[2];
#pragma unroll
        for (int mi = 0; mi < 4; ++mi)
            af[mi] = *(const bf16x8*)&As[(wm * 64 + mi * 16 + rA) * 32 + q8];
#pragma unroll
        for (int ni = 0; ni < 2; ++ni)
            bfr[ni] = *(const bf16x8*)&Bs[(wn * 32 + ni * 16 + rA) * 32 + q8];
#pragma unroll
        for (int mi = 0; mi < 4; ++mi)
#pragma unroll
            for (int ni = 0; ni < 2; ++ni)
                acc[mi][ni] = __builtin_amdgcn_mfma_f32_16x16x32_bf16(af[mi], bfr[ni], acc[mi][ni], 0, 0, 0);
        __syncthreads();
    }
    const int rowb = mt * 128 + wm * 64 + (lane >> 4) * 4;
    const int colb = nt * 64 + wn * 32 + (lane & 15);
#pragma unroll
    for (int mi = 0; mi < 4; ++mi)
#pragma unroll
        for (int ni = 0; ni < 2; ++ni)
#pragma unroll
            for (int rg = 0; rg < 4; ++rg)
                feats[(size_t)(rowb + mi * 16 + rg) * 512 + colb + ni * 16] = acc[mi][ni][rg];
}

// ---------------------------------------------------------------------------
// Kernel A3: one wave per token: rmsnorm(feats_pre, w_tok) -> silu -> W_proj.
// ---------------------------------------------------------------------------
__global__ __launch_bounds__(64) void k_params(
    const float* __restrict__ feats_pre, const float* __restrict__ w_tok,
    const float* __restrict__ W_proj, float* __restrict__ params) {
    const int tk = blockIdx.x;
    const int lane = threadIdx.x;
    const int d0 = lane * 8;
    const float* fp = feats_pre + (size_t)tk * 512 + d0;
    const float4 f0 = *(const float4*)&fp[0];
    const float4 f1 = *(const float4*)&fp[4];
    float ss = f0.x * f0.x + f0.y * f0.y + f0.z * f0.z + f0.w * f0.w
             + f1.x * f1.x + f1.y * f1.y + f1.z * f1.z + f1.w * f1.w;
#pragma unroll
    for (int off = 32; off > 0; off >>= 1) ss += __shfl_down(ss, off);
    ss = __shfl(ss, 0);
    const float rms = rsqrtf(ss * (1.0f / 512.0f) + EPS);

    const float4 wt0 = *(const float4*)&w_tok[d0];
    const float4 wt1 = *(const float4*)&w_tok[d0 + 4];
    float fv[8] = {f0.x, f0.y, f0.z, f0.w, f1.x, f1.y, f1.z, f1.w};
    float wv[8] = {wt0.x, wt0.y, wt0.z, wt0.w, wt1.x, wt1.y, wt1.z, wt1.w};
    float s[8];
#pragma unroll
    for (int j = 0; j < 8; ++j) {
        const float v = fv[j] * wv[j] * rms;
        s[j] = v / (1.0f + expf(-v));
    }
    float p[3];
#pragma unroll
    for (int q = 0; q < 3; ++q) {
        const float* Wp = W_proj + (size_t)q * 512 + d0;
        const float4 a = *(const float4*)&Wp[0];
        const float4 c = *(const float4*)&Wp[4];
        p[q] = s[0] * a.x + s[1] * a.y + s[2] * a.z + s[3] * a.w
             + s[4] * c.x + s[5] * c.y + s[6] * c.z + s[7] * c.w;
#pragma unroll
        for (int off = 32; off > 0; off >>= 1) p[q] += __shfl_down(p[q], off);
    }
    if (lane == 0) {
        float* po = params + (size_t)tk * 4;
        po[0] = 1.0f + p[0];
        po[1] = p[1];
        po[2] = 1.0f / (1.0f + expf(-p[2]));
    }
}

// ---------------------------------------------------------------------------
// Kernel CP: char prep. One wave per compact slot j: rmsnorm -> modulated silu
// -> bf16 h row; also stores cnp = (1-g)*cn as bf16 and g per slot.
// Zeroes h pad rows up to cnt rounded to 128.
// ---------------------------------------------------------------------------
__global__ __launch_bounds__(256) void k_prep(
    const float* __restrict__ chars, const float* __restrict__ w_char,
    const float* __restrict__ params, const int* __restrict__ v_list,
    const int* __restrict__ counts, short* __restrict__ hb,
    short* __restrict__ cnp, float* __restrict__ g_l) {
    const int tid = threadIdx.x, lane = tid & 63, wave = tid >> 6;
    const int b = blockIdx.x >> 10;
    const int j = (blockIdx.x & 1023) * 4 + wave;
    const int cnt = counts[b];
    const int cpad = (cnt + 127) & ~127;
    if (j >= cpad) return;
    short* hrow = hb + ((size_t)(b << 12) + j) * 512 + lane * 8;
    if (j >= cnt) {
        *(bf16x8*)hrow = (bf16x8)0;
        return;
    }
    const int i = v_list[(b << 12) + j];
    const float* xp = chars + ((size_t)(b << 12) + i) * 512 + lane * 8;
    const float4 x0 = *(const float4*)&xp[0];
    const float4 x1 = *(const float4*)&xp[4];
    float ss = x0.x * x0.x + x0.y * x0.y + x0.z * x0.z + x0.w * x0.w
             + x1.x * x1.x + x1.y * x1.y + x1.z * x1.z + x1.w * x1.w;
#pragma unroll
    for (int off = 32; off > 0; off >>= 1) ss += __shfl_down(ss, off);
    ss = __shfl(ss, 0);
    const float rms = rsqrtf(ss * (1.0f / 512.0f) + EPS);
    const float* pp = params + (size_t)((b << 8) + (i >> 4)) * 4;
    const float s1 = pp[0], sh = pp[1], g = pp[2];
    const float4 w0 = *(const float4*)&w_char[lane * 8];
    const float4 w1 = *(const float4*)&w_char[lane * 8 + 4];
    float xv[8] = {x0.x, x0.y, x0.z, x0.w, x1.x, x1.y, x1.z, x1.w};
    float wv[8] = {w0.x, w0.y, w0.z, w0.w, w1.x, w1.y, w1.z, w1.w};
    bf16x8 oh, oc;
    const float gm1 = 1.0f - g;
#pragma unroll
    for (int q = 0; q < 8; ++q) {
        const float cn = wv[q] * xv[q] * rms;
        const float a = cn * s1 + sh;
        oh[q] = f2bf(a / (1.0f + expf(-a)));
        oc[q] = f2bf(gm1 * cn);
    }
    *(bf16x8*)hrow = oh;
    *(bf16x8*)(cnp + ((size_t)(b << 12) + j) * 512 + lane * 8) = oc;
    if (lane == 0) g_l[(b << 12) + j] = g;
}

// ---------------------------------------------------------------------------
// Kernel GF: fusion GEMM out[j<cnt] = g*(h @ Wfus^T) + cnp; rows j>=cnt get
// filler. bf16 MFMA 128x128 tiles over compacted rows. Epilogue transposes acc
// through LDS with stride-140 rows (16B-aligned, 2-way-free writes,
// conflict-free b128 reads) for coalesced float4 stores.
// Block swizzle keeps the 4 nt-siblings of one (b,mt) on the same XCD.
// ---------------------------------------------------------------------------
__global__ __launch_bounds__(256) void k_gemm_fus(
    const short* __restrict__ hb, const short* __restrict__ Wbf,
    const short* __restrict__ cnp, const float* __restrict__ g_l,
    const float* __restrict__ filler, const int* __restrict__ counts,
    float* __restrict__ out) {
    __shared__ union SM {
        struct { short A[128 * 32]; short B[128 * 32]; } ab;
        float ep[32][140];
    } sm;
    __shared__ float g_s[128];
    const int tid = threadIdx.x, lane = tid & 63, w = tid >> 6;
    // swizzled decode: blockIdx = (g&7) | ((g>>3)*4 + nt) << 3, g = b*32+mt
    const int low3 = blockIdx.x & 7;
    const int rest = blockIdx.x >> 3;
    const int nt = rest & 3;
    const int g = ((rest >> 2) << 3) | low3;
    const int b = g >> 5;
    const int mt = g & 31;
    const int cnt = counts[b];
    const int row0 = mt * 128;
    const int r5 = tid >> 3;            // 0..31: staged row
    const int c0 = (tid & 7) * 4;       // within-tile col base (+q*32)
    const int cgb = nt * 128;

    if (row0 >= cnt) {
        // fill-only tile
        float4 flr[4];
#pragma unroll
        for (int q = 0; q < 4; ++q) flr[q] = *(const float4*)&filler[cgb + c0 + q * 32];
#pragma unroll
        for (int rr = 0; rr < 4; ++rr) {
            const int j = row0 + rr * 32 + r5;
            float* op = out + ((size_t)(b << 12) + j) * 512 + cgb + c0;
#pragma unroll
            for (int q = 0; q < 4; ++q) *(float4*)&op[q * 32] = flr[q];
        }
        return;
    }
    const int wm = w >> 1, wn = w & 1;

    if (tid < 128) {
        const int j = row0 + tid;
        g_s[tid] = (j < cnt) ? g_l[(b << 12) + j] : 0.f;
    }

    const short* hA = hb + ((size_t)(b << 12) + row0) * 512;
    const short* wB = Wbf + (size_t)nt * 128 * 512;

    f32x4 acc[4][4];
#pragma unroll
    for (int mi = 0; mi < 4; ++mi)
#pragma unroll
        for (int ni = 0; ni < 4; ++ni) acc[mi][ni] = (f32x4)0.f;

    const int rA = lane & 15, q8 = (lane >> 4) * 8;
    for (int kk = 0; kk < 512; kk += 32) {
#pragma unroll
        for (int q = 0; q < 2; ++q) {
            const int cid = (w * 2 + q) * 64 + lane;
            const int r = cid >> 2, kc = cid & 3;
            const size_t go = (size_t)r * 512 + kk + kc * 8;
            __builtin_amdgcn_global_load_lds(
                (const __attribute__((address_space(1))) uint32_t*)(hA + go),
                (__attribute__((address_space(3))) uint32_t*)&sm.ab.A[(w * 2 + q) * 512], 16, 0, 0);
            __builtin_amdgcn_global_load_lds(
                (const __attribute__((address_space(1))) uint32_t*)(wB + go),
                (__attribute__((address_space(3))) uint32_t*)&sm.ab.B[(w * 2 + q) * 512], 16, 0, 0);
        }
        __syncthreads();
        bf16x8 af[4], bfr[4];
#pragma unroll
        for (int mi = 0; mi < 4; ++mi)
            af[mi] = *(const bf16x8*)&sm.ab.A[(wm * 64 + mi * 16 + rA) * 32 + q8];
#pragma unroll
        for (int ni = 0; ni < 4; ++ni)
            bfr[ni] = *(const bf16x8*)&sm.ab.B[(wn * 64 + ni * 16 + rA) * 32 + q8];
#pragma unroll
        for (int mi = 0; mi < 4; ++mi)
#pragma unroll
            for (int ni = 0; ni < 4; ++ni)
                acc[mi][ni] = __builtin_amdgcn_mfma_f32_16x16x32_bf16(af[mi], bfr[ni], acc[mi][ni], 0, 0, 0);
        __syncthreads();
    }

    // Epilogue: 4 passes of 32 rows x 128 cols via LDS transpose.
#pragma unroll
    for (int mi = 0; mi < 4; ++mi) {
#pragma unroll
        for (int ni = 0; ni < 4; ++ni)
#pragma unroll
            for (int rg = 0; rg < 4; ++rg)
                sm.ep[wm * 16 + (lane >> 4) * 4 + rg][wn * 64 + ni * 16 + (lane & 15)] = acc[mi][ni][rg];
        __syncthreads();
        const int jl = (r5 < 16) ? (mi * 16 + r5) : (64 + mi * 16 + (r5 - 16));
        const int j = row0 + jl;
        float* op = out + ((size_t)(b << 12) + j) * 512 + cgb + c0;
        if (j < cnt) {
            const float gg = g_s[jl];
            const short* cp = cnp + ((size_t)(b << 12) + j) * 512 + cgb + c0;
#pragma unroll
            for (int q = 0; q < 4; ++q) {
                const short4 cv = *(const short4*)(cp + q * 32);
                const float4 e = *(const float4*)&sm.ep[r5][c0 + q * 32];
                float4 o;
                o.x = gg * e.x + bf2f(cv.x);
                o.y = gg * e.y + bf2f(cv.y);
                o.z = gg * e.z + bf2f(cv.z);
                o.w = gg * e.w + bf2f(cv.w);
                *(float4*)&op[q * 32] = o;
            }
        } else {
#pragma unroll
            for (int q = 0; q < 4; ++q)
                *(float4*)&op[q * 32] = *(const float4*)&filler[cgb + c0 + q * 32];
        }
        __syncthreads();
    }
}

// ---------------------------------------------------------------------------
extern "C" void kernel_launch(void* const* d_in, const int* in_sizes, int n_in,
                              void* d_out, int out_size, void* d_ws, size_t ws_size,
                              hipStream_t stream) {
    const float* tokens = (const float*)d_in[0];
    const float* chars  = (const float*)d_in[2];
    const void*  cmask  = d_in[3];
    const float* filler = (const float*)d_in[4];
    const float* w_pre  = (const float*)d_in[5];
    const float* w_tok  = (const float*)d_in[6];
    const float* w_char = (const float*)d_in[7];
    const float* W_down = (const float*)d_in[8];
    const float* W_proj = (const float*)d_in[9];
    const float* W_fus  = (const float*)d_in[10];
    float* out = (float*)d_out;

    // workspace layout (~146 MB)
    float* feats_pre = (float*)d_ws;                          // 4096*512 f32
    float* params    = feats_pre + (size_t)4096 * 512;        // 4096*4 f32
    int*   counts    = (int*)(params + (size_t)4096 * 4);     // 16
    int*   v_list    = counts + 16;                           // 65536
    float* g_l       = (float*)(v_list + 65536);              // 65536
    short* Wbf       = (short*)(g_l + 65536);                 // 512*512 bf16
    short* Wdbf      = Wbf + (size_t)512 * 512;               // 512*1024 bf16
    short* tokbf     = Wdbf + (size_t)512 * 1024;             // 4096*1024 bf16
    short* hb        = tokbf + (size_t)4096 * 1024;           // 16*4096*512 bf16
    short* cnp       = hb + (size_t)16 * 4096 * 512;          // 16*4096*512 bf16

    k_scan_conv<<<784, 256, 0, stream>>>(cmask, v_list, counts,
                                         W_fus, Wbf, 65536, W_down, Wdbf, 131072);
    k_tokprep<<<1024, 256, 0, stream>>>(tokens, w_pre, tokbf);
    k_gemm_tok<<<256, 256, 0, stream>>>(tokbf, Wdbf, feats_pre);
    k_params<<<4096, 64, 0, stream>>>(feats_pre, w_tok, W_proj, params);
    k_prep<<<16384, 256, 0, stream>>>(chars, w_char, params, v_list, counts, hb, cnp, g_l);
    k_gemm_fus<<<2048, 256, 0, stream>>>(hb, Wbf, cnp, g_l, filler, counts, out);
}